// Round 16
// baseline (70.321 us; speedup 1.0000x reference)
//
// R16: R15 retry with the compile fix — nontemporal load via clang
// ext_vector_type(4) (HIP float4 is a class; builtin rejects it). Same
// experiment: nontemporal x-stream + out-store, unroll 4, negated-bias,
// expect-hint, 32-bit offsets.
// Poison ledger: hand dual-chain = no-store poison (R3/4/5/7); compiler
// unroll of this body = safe (R14); ext_vector nontemporal = compiled in R3
// (failure there fully attributed to dual-chain via R4/R7 controls).
// Revert anchor: R14 (54.44 us).
#include <hip/hip_runtime.h>
#include <stdint.h>

typedef unsigned long long u64;
typedef float f32x4 __attribute__((ext_vector_type(4)));

// Workspace layout (u64 words in d_ws):
//   [0..511]   w1 packed: row r (0..127), word j (0..3); bit l = w1[r][l*4+j] < 0
//   [512..639] w2 packed: row r (0..63), word j (0..1); bit l = w2[r][j*64+l] < 0
//   [640]      w3 packed: bit l = w3[l] < 0
// Weights treated as nonzero (normal*0.1). Hidden activations ternary
// (exact-zero preact ~5%/elem) -> nonzero masks. x rows take the exact
// ternary slow path only when they contain an exact 0.0f (product-ballot
// detect; false positives harmless).

__global__ __launch_bounds__(256) void pack_weights(
    const float* __restrict__ w1, const float* __restrict__ w2,
    const float* __restrict__ w3, u64* __restrict__ wp)
{
    int t = blockIdx.x * blockDim.x + threadIdx.x;
    if (t < 512) {
        int r = t >> 2, j = t & 3;
        const float* src = w1 + r * 256 + j;
        u64 word = 0;
        #pragma unroll
        for (int l = 0; l < 64; ++l)
            word |= (u64)(src[l * 4] < 0.0f) << l;
        wp[t] = word;
    } else if (t < 640) {
        int idx = t - 512;
        int r = idx >> 1, j = idx & 1;
        const float* src = w2 + r * 128 + j * 64;
        u64 word = 0;
        #pragma unroll
        for (int l = 0; l < 64; ++l)
            word |= (u64)(src[l] < 0.0f) << l;
        wp[t] = word;
    } else if (t == 640) {
        u64 word = 0;
        #pragma unroll
        for (int l = 0; l < 64; ++l)
            word |= (u64)(w3[l] < 0.0f) << l;
        wp[t] = word;
    }
}

__global__ __launch_bounds__(256) void xnor_fwd(
    const float* __restrict__ x,
    const float* __restrict__ b1, const float* __restrict__ b2,
    const float* __restrict__ b3,
    const u64* __restrict__ w1p, const u64* __restrict__ w2p,
    const u64* __restrict__ w3p,
    float* __restrict__ out, int B)
{
    const int lane = threadIdx.x & 63;
    const int wib  = threadIdx.x >> 6;
    const int wpb  = blockDim.x >> 6;
    const int g    = blockIdx.x * wpb + wib;      // wave id
    const int nwav = gridDim.x * wpb;             // 8192

    // Per-lane weight fragments (loaded once; coalesced):
    // lane l owns w1 rows l and l+64, and w2 row l.
    u64 w1a[4], w1b[4], w2r[2];
    #pragma unroll
    for (int j = 0; j < 4; ++j) {
        w1a[j] = w1p[lane * 4 + j];
        w1b[j] = w1p[(lane + 64) * 4 + j];
    }
    w2r[0] = w2p[lane * 2 + 0];
    w2r[1] = w2p[lane * 2 + 1];
    const u64 w3w = w3p[0];
    // Negated-bias thresholds: test (float)K < -b instead of K+b < 0.
    const float nb1a = -b1[lane], nb1b = -b1[lane + 64];
    const float nb2v = -b2[lane];
    const float b3v  = b3[0];

    const int iters = B / nwav;                   // 32 at B=262144
    const unsigned stride = (unsigned)nwav << 10; // row stride in bytes
    unsigned off = ((unsigned)g << 10) + ((unsigned)lane << 4);
    const char* xb = (const char*)x;
    int row = g;

    #pragma unroll 4
    for (int it = 0; it < iters; ++it, row += nwav, off += stride) {
        // 1 KB coalesced row load; nontemporal: x is streamed exactly once.
        const f32x4 xv = __builtin_nontemporal_load(
            reinterpret_cast<const f32x4*>(xb + off));

        // Sign ballots (word j, bit l <-> element l*4+j, matching w1p layout).
        const u64 sx0 = __ballot(xv[0] < 0.0f);
        const u64 sx1 = __ballot(xv[1] < 0.0f);
        const u64 sx2 = __ballot(xv[2] < 0.0f);
        const u64 sx3 = __ballot(xv[3] < 0.0f);

        // Zero-detect: prod==0 iff some element is +/-0.0f (no overflow at
        // |x|<~6; underflow false-positives just take the exact path).
        const float prod = xv[0] * xv[1] * xv[2] * xv[3];
        const u64 zb = __ballot(prod == 0.0f);

        int pa, pb, nzx;
        if (__builtin_expect(zb == 0ull, 1)) {
            // Fast path (~always): all 256 elements nonzero.
            nzx = 256;
            pa = __popcll(sx0 ^ w1a[0]) + __popcll(sx1 ^ w1a[1])
               + __popcll(sx2 ^ w1a[2]) + __popcll(sx3 ^ w1a[3]);
            pb = __popcll(sx0 ^ w1b[0]) + __popcll(sx1 ^ w1b[1])
               + __popcll(sx2 ^ w1b[2]) + __popcll(sx3 ^ w1b[3]);
        } else {
            // Exact ternary path (rare): mask out zero elements.
            const u64 mx0 = __ballot(xv[0] != 0.0f);
            const u64 mx1 = __ballot(xv[1] != 0.0f);
            const u64 mx2 = __ballot(xv[2] != 0.0f);
            const u64 mx3 = __ballot(xv[3] != 0.0f);
            nzx = __popcll(mx0) + __popcll(mx1) + __popcll(mx2) + __popcll(mx3);
            pa = __popcll((sx0 ^ w1a[0]) & mx0) + __popcll((sx1 ^ w1a[1]) & mx1)
               + __popcll((sx2 ^ w1a[2]) & mx2) + __popcll((sx3 ^ w1a[3]) & mx3);
            pb = __popcll((sx0 ^ w1b[0]) & mx0) + __popcll((sx1 ^ w1b[1]) & mx1)
               + __popcll((sx2 ^ w1b[2]) & mx2) + __popcll((sx3 ^ w1b[3]) & mx3);
        }

        // Preact K vs threshold -b: sign = K < -b; nonzero = K != -b.
        const float fa = (float)(nzx - 2 * pa);
        const float fb = (float)(nzx - 2 * pb);

        // h1 ternary: word 0 = rows 0..63, word 1 = rows 64..127.
        const u64 s1_0 = __ballot(fa < nb1a);
        const u64 s1_1 = __ballot(fb < nb1b);
        const u64 m1_0 = __ballot(fa != nb1a);
        const u64 m1_1 = __ballot(fb != nb1b);
        const int nz1 = __popcll(m1_0) + __popcll(m1_1);

        // Layer 2: row 'lane' of w2.
        const int p2 = __popcll((s1_0 ^ w2r[0]) & m1_0)
                     + __popcll((s1_1 ^ w2r[1]) & m1_1);
        const float fc = (float)(nz1 - 2 * p2);

        // h2 ternary (64 values).
        const u64 s2 = __ballot(fc < nb2v);
        const u64 m2 = __ballot(fc != nb2v);
        const int nz2 = __popcll(m2);

        // Layer 3 + sigmoid (wave-uniform).
        const int p3 = __popcll((s2 ^ w3w) & m2);
        const float t3 = (float)(nz2 - 2 * p3) + b3v;
        const float res = 1.0f / (1.0f + __expf(-t3));
        if (lane == 0) __builtin_nontemporal_store(res, &out[row]);
    }

    // Tail (B % nwav rows; not hit at B=262144): wave g takes one extra row.
    const int trow = iters * nwav + g;
    if (trow < B) {
        const float4 xv = *reinterpret_cast<const float4*>(
            xb + (unsigned)trow * 1024u + ((unsigned)lane << 4));
        const u64 sx0 = __ballot(xv.x < 0.0f);
        const u64 sx1 = __ballot(xv.y < 0.0f);
        const u64 sx2 = __ballot(xv.z < 0.0f);
        const u64 sx3 = __ballot(xv.w < 0.0f);
        const u64 mx0 = __ballot(xv.x != 0.0f);
        const u64 mx1 = __ballot(xv.y != 0.0f);
        const u64 mx2 = __ballot(xv.z != 0.0f);
        const u64 mx3 = __ballot(xv.w != 0.0f);
        const int nzx = __popcll(mx0) + __popcll(mx1) + __popcll(mx2) + __popcll(mx3);
        const int pa = __popcll((sx0 ^ w1a[0]) & mx0) + __popcll((sx1 ^ w1a[1]) & mx1)
                     + __popcll((sx2 ^ w1a[2]) & mx2) + __popcll((sx3 ^ w1a[3]) & mx3);
        const int pb = __popcll((sx0 ^ w1b[0]) & mx0) + __popcll((sx1 ^ w1b[1]) & mx1)
                     + __popcll((sx2 ^ w1b[2]) & mx2) + __popcll((sx3 ^ w1b[3]) & mx3);
        const float fa = (float)(nzx - 2 * pa);
        const float fb = (float)(nzx - 2 * pb);
        const u64 s1_0 = __ballot(fa < nb1a);
        const u64 s1_1 = __ballot(fb < nb1b);
        const u64 m1_0 = __ballot(fa != nb1a);
        const u64 m1_1 = __ballot(fb != nb1b);
        const int nz1 = __popcll(m1_0) + __popcll(m1_1);
        const int p2 = __popcll((s1_0 ^ w2r[0]) & m1_0)
                     + __popcll((s1_1 ^ w2r[1]) & m1_1);
        const float fc = (float)(nz1 - 2 * p2);
        const u64 s2 = __ballot(fc < nb2v);
        const u64 m2 = __ballot(fc != nb2v);
        const int nz2 = __popcll(m2);
        const int p3 = __popcll((s2 ^ w3w) & m2);
        const float t3 = (float)(nz2 - 2 * p3) + b3v;
        const float res = 1.0f / (1.0f + __expf(-t3));
        if (lane == 0) out[trow] = res;
    }
}

extern "C" void kernel_launch(void* const* d_in, const int* in_sizes, int n_in,
                              void* d_out, int out_size, void* d_ws, size_t ws_size,
                              hipStream_t stream)
{
    const float* x  = (const float*)d_in[0];
    const float* w1 = (const float*)d_in[1];
    const float* b1 = (const float*)d_in[2];
    const float* w2 = (const float*)d_in[3];
    const float* b2 = (const float*)d_in[4];
    const float* w3 = (const float*)d_in[5];
    const float* b3 = (const float*)d_in[6];
    float* out = (float*)d_out;
    const int B = in_sizes[0] / 256;

    u64* wp = (u64*)d_ws;   // needs 641*8 = 5128 bytes of scratch

    pack_weights<<<3, 256, 0, stream>>>(w1, w2, w3, wp);

    // 2048 blocks * 4 waves = 8192 waves; 32 rows per wave, grid-strided.
    const int blocks = 2048;
    xnor_fwd<<<blocks, 256, 0, stream>>>(x, b1, b2, b3,
                                         wp, wp + 512, wp + 640, out, B);
}

// Round 17
// 54.410 us; speedup vs baseline: 1.2924x; 1.2924x over previous
//
// R17: byte-exact R14 champion (54.44 us) with ONE change: unroll 2 -> 4
// (isolating R16's unroll from its convicted nontemporal confound).
// Poison ledger: hand dual-chain = no-store poison (R3/4/5/7); nontemporal
// x-load = perf poison, bypasses the L2/L3 assist on the 256MB stream (R16,
// +16 us); compiler unroll of this body = safe (R14).
// Revert anchor: R14 (54.44 us). If this is neutral, R14 is the roofline.
#include <hip/hip_runtime.h>
#include <stdint.h>

typedef unsigned long long u64;

// Workspace layout (u64 words in d_ws):
//   [0..511]   w1 packed: row r (0..127), word j (0..3); bit l = w1[r][l*4+j] < 0
//   [512..639] w2 packed: row r (0..63), word j (0..1); bit l = w2[r][j*64+l] < 0
//   [640]      w3 packed: bit l = w3[l] < 0
// Weights treated as nonzero (normal*0.1). Hidden activations ternary
// (exact-zero preact ~5%/elem) -> nonzero masks. x rows take the exact
// ternary slow path only when they contain an exact 0.0f (product-ballot
// detect; false positives harmless).

__global__ __launch_bounds__(256) void pack_weights(
    const float* __restrict__ w1, const float* __restrict__ w2,
    const float* __restrict__ w3, u64* __restrict__ wp)
{
    int t = blockIdx.x * blockDim.x + threadIdx.x;
    if (t < 512) {
        int r = t >> 2, j = t & 3;
        const float* src = w1 + r * 256 + j;
        u64 word = 0;
        #pragma unroll
        for (int l = 0; l < 64; ++l)
            word |= (u64)(src[l * 4] < 0.0f) << l;
        wp[t] = word;
    } else if (t < 640) {
        int idx = t - 512;
        int r = idx >> 1, j = idx & 1;
        const float* src = w2 + r * 128 + j * 64;
        u64 word = 0;
        #pragma unroll
        for (int l = 0; l < 64; ++l)
            word |= (u64)(src[l] < 0.0f) << l;
        wp[t] = word;
    } else if (t == 640) {
        u64 word = 0;
        #pragma unroll
        for (int l = 0; l < 64; ++l)
            word |= (u64)(w3[l] < 0.0f) << l;
        wp[t] = word;
    }
}

__global__ __launch_bounds__(256) void xnor_fwd(
    const float* __restrict__ x,
    const float* __restrict__ b1, const float* __restrict__ b2,
    const float* __restrict__ b3,
    const u64* __restrict__ w1p, const u64* __restrict__ w2p,
    const u64* __restrict__ w3p,
    float* __restrict__ out, int B)
{
    const int lane = threadIdx.x & 63;
    const int wib  = threadIdx.x >> 6;
    const int wpb  = blockDim.x >> 6;
    const int g    = blockIdx.x * wpb + wib;      // wave id
    const int nwav = gridDim.x * wpb;             // 8192

    // Per-lane weight fragments (loaded once; coalesced):
    // lane l owns w1 rows l and l+64, and w2 row l.
    u64 w1a[4], w1b[4], w2r[2];
    #pragma unroll
    for (int j = 0; j < 4; ++j) {
        w1a[j] = w1p[lane * 4 + j];
        w1b[j] = w1p[(lane + 64) * 4 + j];
    }
    w2r[0] = w2p[lane * 2 + 0];
    w2r[1] = w2p[lane * 2 + 1];
    const u64 w3w = w3p[0];
    // Negated-bias thresholds: test (float)K < -b instead of K+b < 0.
    const float nb1a = -b1[lane], nb1b = -b1[lane + 64];
    const float nb2v = -b2[lane];
    const float b3v  = b3[0];

    const int iters = B / nwav;                   // 32 at B=262144
    const unsigned stride = (unsigned)nwav << 10; // row stride in bytes
    unsigned off = ((unsigned)g << 10) + ((unsigned)lane << 4);
    const char* xb = (const char*)x;
    int row = g;

    #pragma unroll 4
    for (int it = 0; it < iters; ++it, row += nwav, off += stride) {
        // 1 KB coalesced row load: lane l takes elements l*4 .. l*4+3.
        const float4 xv = *reinterpret_cast<const float4*>(xb + off);

        // Sign ballots (word j, bit l <-> element l*4+j, matching w1p layout).
        const u64 sx0 = __ballot(xv.x < 0.0f);
        const u64 sx1 = __ballot(xv.y < 0.0f);
        const u64 sx2 = __ballot(xv.z < 0.0f);
        const u64 sx3 = __ballot(xv.w < 0.0f);

        // Zero-detect: prod==0 iff some element is +/-0.0f (no overflow at
        // |x|<~6; underflow false-positives just take the exact path).
        const float prod = xv.x * xv.y * xv.z * xv.w;
        const u64 zb = __ballot(prod == 0.0f);

        int pa, pb, nzx;
        if (__builtin_expect(zb == 0ull, 1)) {
            // Fast path (~always): all 256 elements nonzero.
            nzx = 256;
            pa = __popcll(sx0 ^ w1a[0]) + __popcll(sx1 ^ w1a[1])
               + __popcll(sx2 ^ w1a[2]) + __popcll(sx3 ^ w1a[3]);
            pb = __popcll(sx0 ^ w1b[0]) + __popcll(sx1 ^ w1b[1])
               + __popcll(sx2 ^ w1b[2]) + __popcll(sx3 ^ w1b[3]);
        } else {
            // Exact ternary path (rare): mask out zero elements.
            const u64 mx0 = __ballot(xv.x != 0.0f);
            const u64 mx1 = __ballot(xv.y != 0.0f);
            const u64 mx2 = __ballot(xv.z != 0.0f);
            const u64 mx3 = __ballot(xv.w != 0.0f);
            nzx = __popcll(mx0) + __popcll(mx1) + __popcll(mx2) + __popcll(mx3);
            pa = __popcll((sx0 ^ w1a[0]) & mx0) + __popcll((sx1 ^ w1a[1]) & mx1)
               + __popcll((sx2 ^ w1a[2]) & mx2) + __popcll((sx3 ^ w1a[3]) & mx3);
            pb = __popcll((sx0 ^ w1b[0]) & mx0) + __popcll((sx1 ^ w1b[1]) & mx1)
               + __popcll((sx2 ^ w1b[2]) & mx2) + __popcll((sx3 ^ w1b[3]) & mx3);
        }

        // Preact K vs threshold -b: sign = K < -b; nonzero = K != -b.
        const float fa = (float)(nzx - 2 * pa);
        const float fb = (float)(nzx - 2 * pb);

        // h1 ternary: word 0 = rows 0..63, word 1 = rows 64..127.
        const u64 s1_0 = __ballot(fa < nb1a);
        const u64 s1_1 = __ballot(fb < nb1b);
        const u64 m1_0 = __ballot(fa != nb1a);
        const u64 m1_1 = __ballot(fb != nb1b);
        const int nz1 = __popcll(m1_0) + __popcll(m1_1);

        // Layer 2: row 'lane' of w2.
        const int p2 = __popcll((s1_0 ^ w2r[0]) & m1_0)
                     + __popcll((s1_1 ^ w2r[1]) & m1_1);
        const float fc = (float)(nz1 - 2 * p2);

        // h2 ternary (64 values).
        const u64 s2 = __ballot(fc < nb2v);
        const u64 m2 = __ballot(fc != nb2v);
        const int nz2 = __popcll(m2);

        // Layer 3 + sigmoid (wave-uniform).
        const int p3 = __popcll((s2 ^ w3w) & m2);
        const float t3 = (float)(nz2 - 2 * p3) + b3v;
        const float res = 1.0f / (1.0f + __expf(-t3));
        if (lane == 0) out[row] = res;
    }

    // Tail (B % nwav rows; not hit at B=262144): wave g takes one extra row.
    const int trow = iters * nwav + g;
    if (trow < B) {
        const float4 xv = *reinterpret_cast<const float4*>(
            xb + (unsigned)trow * 1024u + ((unsigned)lane << 4));
        const u64 sx0 = __ballot(xv.x < 0.0f);
        const u64 sx1 = __ballot(xv.y < 0.0f);
        const u64 sx2 = __ballot(xv.z < 0.0f);
        const u64 sx3 = __ballot(xv.w < 0.0f);
        const u64 mx0 = __ballot(xv.x != 0.0f);
        const u64 mx1 = __ballot(xv.y != 0.0f);
        const u64 mx2 = __ballot(xv.z != 0.0f);
        const u64 mx3 = __ballot(xv.w != 0.0f);
        const int nzx = __popcll(mx0) + __popcll(mx1) + __popcll(mx2) + __popcll(mx3);
        const int pa = __popcll((sx0 ^ w1a[0]) & mx0) + __popcll((sx1 ^ w1a[1]) & mx1)
                     + __popcll((sx2 ^ w1a[2]) & mx2) + __popcll((sx3 ^ w1a[3]) & mx3);
        const int pb = __popcll((sx0 ^ w1b[0]) & mx0) + __popcll((sx1 ^ w1b[1]) & mx1)
                     + __popcll((sx2 ^ w1b[2]) & mx2) + __popcll((sx3 ^ w1b[3]) & mx3);
        const float fa = (float)(nzx - 2 * pa);
        const float fb = (float)(nzx - 2 * pb);
        const u64 s1_0 = __ballot(fa < nb1a);
        const u64 s1_1 = __ballot(fb < nb1b);
        const u64 m1_0 = __ballot(fa != nb1a);
        const u64 m1_1 = __ballot(fb != nb1b);
        const int nz1 = __popcll(m1_0) + __popcll(m1_1);
        const int p2 = __popcll((s1_0 ^ w2r[0]) & m1_0)
                     + __popcll((s1_1 ^ w2r[1]) & m1_1);
        const float fc = (float)(nz1 - 2 * p2);
        const u64 s2 = __ballot(fc < nb2v);
        const u64 m2 = __ballot(fc != nb2v);
        const int nz2 = __popcll(m2);
        const int p3 = __popcll((s2 ^ w3w) & m2);
        const float t3 = (float)(nz2 - 2 * p3) + b3v;
        const float res = 1.0f / (1.0f + __expf(-t3));
        if (lane == 0) out[trow] = res;
    }
}

extern "C" void kernel_launch(void* const* d_in, const int* in_sizes, int n_in,
                              void* d_out, int out_size, void* d_ws, size_t ws_size,
                              hipStream_t stream)
{
    const float* x  = (const float*)d_in[0];
    const float* w1 = (const float*)d_in[1];
    const float* b1 = (const float*)d_in[2];
    const float* w2 = (const float*)d_in[3];
    const float* b2 = (const float*)d_in[4];
    const float* w3 = (const float*)d_in[5];
    const float* b3 = (const float*)d_in[6];
    float* out = (float*)d_out;
    const int B = in_sizes[0] / 256;

    u64* wp = (u64*)d_ws;   // needs 641*8 = 5128 bytes of scratch

    pack_weights<<<3, 256, 0, stream>>>(w1, w2, w3, wp);

    // 2048 blocks * 4 waves = 8192 waves; 32 rows per wave, grid-strided.
    const int blocks = 2048;
    xnor_fwd<<<blocks, 256, 0, stream>>>(x, b1, b2, b3,
                                         wp, wp + 512, wp + 640, out, B);
}